// Round 8
// baseline (1185.191 us; speedup 1.0000x reference)
//
#include <hip/hip_runtime.h>
#include <math.h>

#define D_MODEL 512
#define D_INNER 1024
#define DT_RANK 32
#define D_STATE 16
#define D_CONV 4
#define NB_LAYERS 3
#define BATCH 64
#define SEQ 201
#define CITY 200
#define M_ROWS (BATCH * SEQ)   // 12864 = 64*201
#define M_PAD 12928            // 128*101, for 128-row MFMA tiles
#define EPS 1e-5f
#define ST 16                  // scan timestep tile

typedef __attribute__((ext_vector_type(8))) short short8;
typedef __attribute__((ext_vector_type(4))) float f32x4;

__device__ __forceinline__ float sigmoidf_(float x) { return 1.f / (1.f + __expf(-x)); }

__device__ __forceinline__ unsigned short f2b(float f) {  // RNE fp32->bf16
  union { float f; unsigned int u; } v; v.f = f;
  unsigned int r = (v.u + 0x7fff + ((v.u >> 16) & 1)) >> 16;
  return (unsigned short)r;
}
__device__ __forceinline__ float b2f(unsigned short h) {
  union { unsigned int u; float f; } v; v.u = ((unsigned int)h) << 16; return v.f;
}

__device__ __forceinline__ void gload_lds16(const void* g, void* l) {
  __builtin_amdgcn_global_load_lds(
      (const __attribute__((address_space(1))) void*)g,
      (__attribute__((address_space(3))) void*)l, 16, 0, 0);
}

// ---------------- fp32 -> bf16 bulk convert (zero-pad tail to n_total) ----------------
__global__ __launch_bounds__(256) void k_f2b(const float* __restrict__ in,
                                             unsigned short* __restrict__ out,
                                             int n, int n_total) {
  int i = blockIdx.x * 256 + threadIdx.x;
  if (i < n) out[i] = f2b(in[i]);
  else if (i < n_total) out[i] = 0;
}

// ---------------- embed ----------------
__global__ __launch_bounds__(256) void k_embed(const float* __restrict__ x,
                                               const float* __restrict__ W,
                                               const float* __restrict__ b,
                                               float* __restrict__ h) {
  int idx = blockIdx.x * 256 + threadIdx.x;
  if (idx >= M_ROWS * D_MODEL) return;
  int d = idx & (D_MODEL - 1);
  int m = idx >> 9;
  float x0 = x[m * 2 + 0], x1 = x[m * 2 + 1];
  h[idx] = fmaf(x0, W[d * 2 + 0], fmaf(x1, W[d * 2 + 1], b[d]));
}

// ---------------- fused residual add + LayerNorm / RMSNorm ----------------
__global__ __launch_bounds__(256) void k_resid_norm(const float* __restrict__ h,
                                                    float* __restrict__ resid,
                                                    float* __restrict__ out,
                                                    unsigned short* __restrict__ out_b,
                                                    const float* __restrict__ w,
                                                    const float* __restrict__ b,
                                                    int addRes, int mode) {
  int row = blockIdx.x * 4 + (threadIdx.x >> 6);
  int lane = threadIdx.x & 63;
  if (row >= M_ROWS) return;
  const float* hp = h + (size_t)row * D_MODEL;
  float* rp = resid + (size_t)row * D_MODEL;
  float v[8];
#pragma unroll
  for (int j = 0; j < 8; ++j) {
    float t = hp[j * 64 + lane];
    if (addRes) t += rp[j * 64 + lane];
    v[j] = t;
    rp[j * 64 + lane] = t;
  }
  float mu = 0.f, rstd;
  if (mode == 0) {
    float s = 0.f;
#pragma unroll
    for (int j = 0; j < 8; ++j) s += v[j];
#pragma unroll
    for (int o = 1; o < 64; o <<= 1) s += __shfl_xor(s, o);
    mu = s * (1.f / D_MODEL);
    float vs = 0.f;
#pragma unroll
    for (int j = 0; j < 8; ++j) { float d0 = v[j] - mu; vs += d0 * d0; }
#pragma unroll
    for (int o = 1; o < 64; o <<= 1) vs += __shfl_xor(vs, o);
    rstd = rsqrtf(vs * (1.f / D_MODEL) + EPS);
  } else {
    float s = 0.f;
#pragma unroll
    for (int j = 0; j < 8; ++j) s += v[j] * v[j];
#pragma unroll
    for (int o = 1; o < 64; o <<= 1) s += __shfl_xor(s, o);
    rstd = rsqrtf(s * (1.f / D_MODEL) + EPS);
  }
#pragma unroll
  for (int j = 0; j < 8; ++j) {
    int c = j * 64 + lane;
    float o = (v[j] - mu) * rstd * w[c] + b[c];
    if (out) out[(size_t)row * D_MODEL + c] = o;
    if (out_b) out_b[(size_t)row * D_MODEL + c] = f2b(o);
  }
}

// ---------------- bf16 MFMA GEMM: C[M,Nout] = A[M,K]bf16 @ B[N,K]bf16^T ----------
// BM=BN=128, BK=64, 256 threads (4 waves, 2x2 of 64x64). Ngrid%128==0, K%64==0.
// BOUT=1 -> bf16 output, else fp32. Store guarded by m<M && col<Nout.
template <int BOUT>
__global__ __launch_bounds__(256) void k_gemm_mfma(const unsigned short* __restrict__ A,
                                                   const unsigned short* __restrict__ B,
                                                   void* __restrict__ Cv, int ldc,
                                                   int M, int Nout, int K) {
  __shared__ unsigned short lA[128 * 64];
  __shared__ unsigned short lB[128 * 64];
  int tid = threadIdx.x;
  int wave = tid >> 6, lane = tid & 63;
  int bm = blockIdx.y * 128, bn = blockIdx.x * 128;
  int wm = (wave >> 1) * 64, wn = (wave & 1) * 64;
  f32x4 acc[4][4] = {};

  for (int k0 = 0; k0 < K; k0 += 64) {
#pragma unroll
    for (int i = 0; i < 4; ++i) {
      int e = (i * 256 + tid) * 8;   // flat bf16 element in [128][64] tile
      int r = e >> 6, c = e & 63;
      gload_lds16(A + (size_t)(bm + r) * K + k0 + c, &lA[e]);
      gload_lds16(B + (size_t)(bn + r) * K + k0 + c, &lB[e]);
    }
    __syncthreads();
#pragma unroll
    for (int ks = 0; ks < 2; ++ks) {
      int koff = ks * 32 + (lane >> 4) * 8;
      short8 a[4], b[4];
#pragma unroll
      for (int i = 0; i < 4; ++i)
        a[i] = *(const short8*)&lA[(wm + i * 16 + (lane & 15)) * 64 + koff];
#pragma unroll
      for (int j = 0; j < 4; ++j)
        b[j] = *(const short8*)&lB[(wn + j * 16 + (lane & 15)) * 64 + koff];
#pragma unroll
      for (int i = 0; i < 4; ++i)
#pragma unroll
        for (int j = 0; j < 4; ++j)
          acc[i][j] = __builtin_amdgcn_mfma_f32_16x16x32_bf16(a[i], b[j], acc[i][j], 0, 0, 0);
    }
    __syncthreads();
  }
  // C/D layout: col = lane&15, row = (lane>>4)*4 + reg   [m89-verified]
#pragma unroll
  for (int i = 0; i < 4; ++i) {
    int row0 = bm + wm + i * 16 + (lane >> 4) * 4;
#pragma unroll
    for (int j = 0; j < 4; ++j) {
      int col = bn + wn + j * 16 + (lane & 15);
#pragma unroll
      for (int r = 0; r < 4; ++r) {
        int m = row0 + r;
        if (m < M && col < Nout) {
          if (BOUT) ((unsigned short*)Cv)[(size_t)m * ldc + col] = f2b(acc[i][j][r]);
          else ((float*)Cv)[(size_t)m * ldc + col] = acc[i][j][r];
        }
      }
    }
  }
}

// ---------------- depthwise causal conv (width 4) + bias + SiLU; bf16 in/out --------------
__global__ __launch_bounds__(256) void k_conv_silu(const unsigned short* __restrict__ xz,
                                                   const float* __restrict__ cw,
                                                   const float* __restrict__ cb,
                                                   unsigned short* __restrict__ ub) {
  int idx = blockIdx.x * 256 + threadIdx.x;
  if (idx >= M_ROWS * D_INNER) return;
  int d = idx & (D_INNER - 1);
  int m = idx >> 10;
  int l = m % SEQ;
  float acc = cb[d];
#pragma unroll
  for (int k = 0; k < D_CONV; ++k) {
    int ls = l - (D_CONV - 1) + k;
    if (ls >= 0)
      acc = fmaf(cw[d * D_CONV + k], b2f(xz[(size_t)(m - (D_CONV - 1) + k) * 2048 + d]), acc);
  }
  ub[idx] = f2b(acc * sigmoidf_(acc));
}

// ---------------- selective scan + fused dt_proj + D-skip + z-gate ----------------
// 1 thread/channel. Per 16-step tile: stage xdbl rows (dt_r|B|C) to LDS (coalesced),
// batch-issue u/z loads (forced materialization), then 16 sequential steps reading
// LDS via same-address broadcast float4. dt = softplus(dt_r . dtW[d] + bias) in fp32.
__global__ __launch_bounds__(256) void k_scan(const unsigned short* __restrict__ xz,
                                              const unsigned short* __restrict__ ub,
                                              const float* __restrict__ xdbl,
                                              const float* __restrict__ dtW,
                                              const float* __restrict__ dtb,
                                              const float* __restrict__ A_log,
                                              const float* __restrict__ Dv,
                                              unsigned short* __restrict__ yb) {
  __shared__ float lxd[ST][64];
  int tid = threadIdx.x;
  int d = blockIdx.y * 256 + tid;
  int b = blockIdx.x;

  float Wd[DT_RANK];
#pragma unroll
  for (int r = 0; r < DT_RANK; r += 4) {
    float4 w4 = *(const float4*)&dtW[(size_t)d * DT_RANK + r];
    Wd[r] = w4.x; Wd[r + 1] = w4.y; Wd[r + 2] = w4.z; Wd[r + 3] = w4.w;
  }
  float bias = dtb[d];
  float Areg[D_STATE], hst[D_STATE];
#pragma unroll
  for (int n = 0; n < D_STATE; ++n) {
    Areg[n] = -__expf(A_log[d * D_STATE + n]);
    hst[n] = 0.f;
  }
  float Dd = Dv[d];
  size_t row0 = (size_t)b * SEQ;

  for (int t0 = 0; t0 < SEQ; t0 += ST) {
    int nt = SEQ - t0 < ST ? SEQ - t0 : ST;  // wave-uniform
    __syncthreads();
    // stage xdbl rows [t0, t0+nt) -> LDS: nt*16 float4, one per thread
    if (tid < nt * 16) {
      float4 v = *(const float4*)&xdbl[(row0 + t0 + (tid >> 4)) * 64 + (tid & 15) * 4];
      *(float4*)&lxd[tid >> 4][(tid & 15) * 4] = v;
    }
    __syncthreads();
    // batch-issue u/z loads for the tile; force materialization so compiler can't sink
    float u_pre[ST], z_pre[ST];
#pragma unroll
    for (int tt = 0; tt < ST; ++tt) {
      if (tt < nt) {
        size_t m = row0 + t0 + tt;
        u_pre[tt] = b2f(ub[m * D_INNER + d]);
        z_pre[tt] = b2f(xz[m * 2048 + 1024 + d]);
      } else {
        u_pre[tt] = 0.f; z_pre[tt] = 0.f;
      }
    }
#pragma unroll
    for (int tt = 0; tt < ST; ++tt)
      asm volatile("" :: "v"(u_pre[tt]), "v"(z_pre[tt]));
    // sequential steps
#pragma unroll
    for (int tt = 0; tt < ST; ++tt) {
      if (tt < nt) {
        // dt_proj: dot(dt_r, Wd) + bias, softplus
        float dot = bias;
#pragma unroll
        for (int r = 0; r < 8; ++r) {
          float4 q = *(const float4*)&lxd[tt][r * 4];
          dot = fmaf(q.x, Wd[4 * r + 0], dot);
          dot = fmaf(q.y, Wd[4 * r + 1], dot);
          dot = fmaf(q.z, Wd[4 * r + 2], dot);
          dot = fmaf(q.w, Wd[4 * r + 3], dot);
        }
        float dtv = (dot > 20.f) ? dot : log1pf(__expf(dot));
        float uv = u_pre[tt], zv = z_pre[tt];
        float du = dtv * uv;
        float y = 0.f;
#pragma unroll
        for (int q = 0; q < 4; ++q) {
          float4 vb = *(const float4*)&lxd[tt][32 + q * 4];
          float4 vc = *(const float4*)&lxd[tt][48 + q * 4];
          hst[4 * q + 0] = fmaf(__expf(dtv * Areg[4 * q + 0]), hst[4 * q + 0], du * vb.x);
          y = fmaf(hst[4 * q + 0], vc.x, y);
          hst[4 * q + 1] = fmaf(__expf(dtv * Areg[4 * q + 1]), hst[4 * q + 1], du * vb.y);
          y = fmaf(hst[4 * q + 1], vc.y, y);
          hst[4 * q + 2] = fmaf(__expf(dtv * Areg[4 * q + 2]), hst[4 * q + 2], du * vb.z);
          y = fmaf(hst[4 * q + 2], vc.z, y);
          hst[4 * q + 3] = fmaf(__expf(dtv * Areg[4 * q + 3]), hst[4 * q + 3], du * vb.w);
          y = fmaf(hst[4 * q + 3], vc.w, y);
        }
        y = fmaf(Dd, uv, y);
        y = y * (zv * sigmoidf_(zv));
        yb[(row0 + t0 + tt) * D_INNER + d] = f2b(y);
      }
    }
  }
}

extern "C" void kernel_launch(void* const* d_in, const int* in_sizes, int n_in,
                              void* d_out, int out_size, void* d_ws, size_t ws_size,
                              hipStream_t stream) {
  const float* x        = (const float*)d_in[0];
  const float* embed_W  = (const float*)d_in[2];
  const float* embed_b  = (const float*)d_in[3];
  const float* norm_w   = (const float*)d_in[4];
  const float* norm_b   = (const float*)d_in[5];
  const float* in_W     = (const float*)d_in[6];
  const float* conv_w   = (const float*)d_in[7];
  const float* conv_b   = (const float*)d_in[8];
  const float* xproj_W  = (const float*)d_in[9];
  const float* dtproj_W = (const float*)d_in[10];
  const float* dtproj_b = (const float*)d_in[11];
  const float* A_log    = (const float*)d_in[12];
  const float* Dskip    = (const float*)d_in[13];
  const float* out_W    = (const float*)d_in[14];
  const float* normf_w  = (const float*)d_in[15];
  const float* normf_b  = (const float*)d_in[16];
  const float* head_W   = (const float*)d_in[17];
  float* out = (float*)d_out;

  // fp32: res 512 + h 512 + xdbl 64 = M*1088 (56 MiB)
  // bf16: xz M*2048 + ub/yb M_PAD*2048 + weights (~1.7M elems)  (~109 MiB)
  size_t f32_elems = (size_t)M_ROWS * 1088;
  size_t bf16_elems = (size_t)M_ROWS * 2048 + (size_t)M_PAD * 2048 +
                      2048 * 512 + 512 * 1024 + 128 * 1024;
  size_t need = f32_elems * 4 + bf16_elems * 2;
  if (ws_size < need) return;

  float* ws = (float*)d_ws;
  float* buf_res  = ws;                                   // M*512
  float* buf_h    = buf_res  + (size_t)M_ROWS * 512;      // M*512
  float* buf_xdbl = buf_h    + (size_t)M_ROWS * 512;      // M*64
  unsigned short* buf_xz  = (unsigned short*)(buf_xdbl + (size_t)M_ROWS * 64); // M*2048 (xc|z)
  unsigned short* buf_ub  = buf_xz + (size_t)M_ROWS * 2048;  // M_PAD*1024
  unsigned short* buf_yb  = buf_ub + (size_t)M_PAD * 1024;   // M_PAD*1024 (alias hnb)
  unsigned short* buf_hnb = buf_yb;                          // M_PAD*512 (hn dead before scan)
  unsigned short* buf_wib = buf_yb + (size_t)M_PAD * 1024;   // 2048*512 (in_W; head_W after loop)
  unsigned short* buf_wob = buf_wib + (size_t)2048 * 512;    // 512*1024 (out_W)
  unsigned short* buf_wxb = buf_wob + (size_t)512 * 1024;    // 128*1024 (xproj_W padded)

  dim3 blk(256);

  k_embed<<<(M_ROWS * D_MODEL + 255) / 256, blk, 0, stream>>>(x, embed_W, embed_b, buf_h);

  for (int i = 0; i < NB_LAYERS; ++i) {
    // weights -> bf16 (per layer); xproj_W zero-padded 64->128 rows
    k_f2b<<<(2048 * 512 + 255) / 256, blk, 0, stream>>>(
        in_W + (size_t)i * 2048 * D_MODEL, buf_wib, 2048 * 512, 2048 * 512);
    k_f2b<<<(512 * 1024 + 255) / 256, blk, 0, stream>>>(
        out_W + (size_t)i * D_MODEL * D_INNER, buf_wob, 512 * 1024, 512 * 1024);
    k_f2b<<<(128 * 1024 + 255) / 256, blk, 0, stream>>>(
        xproj_W + (size_t)i * 64 * D_INNER, buf_wxb, 64 * 1024, 128 * 1024);

    // residual update + layernorm -> hn (bf16)
    k_resid_norm<<<(M_ROWS + 3) / 4, blk, 0, stream>>>(
        buf_h, buf_res, nullptr, buf_hnb, norm_w + i * D_MODEL, norm_b + i * D_MODEL,
        i > 0 ? 1 : 0, 0);

    // in_proj (bf16 MFMA, bf16 out): xz = hn @ in_W^T   (M, 2048)
    k_gemm_mfma<1><<<dim3(2048 / 128, M_PAD / 128), blk, 0, stream>>>(
        buf_hnb, buf_wib, buf_xz, 2048, M_ROWS, 2048, 512);

    // conv + silu -> u (bf16 in/out)
    k_conv_silu<<<(M_ROWS * D_INNER + 255) / 256, blk, 0, stream>>>(
        buf_xz, conv_w + (size_t)i * D_INNER * D_CONV, conv_b + (size_t)i * D_INNER, buf_ub);

    // x_proj (bf16 MFMA, fp32 out): xdbl = u @ xproj_W^T   (M, 64), N padded to 128
    k_gemm_mfma<0><<<dim3(1, M_PAD / 128), blk, 0, stream>>>(
        buf_ub, buf_wxb, buf_xdbl, 64, M_ROWS, 64, 1024);

    // selective scan (fused dt_proj) -> y (bf16, overwrites hn region; hn is dead)
    k_scan<<<dim3(BATCH, D_INNER / 256), blk, 0, stream>>>(
        buf_xz, buf_ub, buf_xdbl,
        dtproj_W + (size_t)i * D_INNER * DT_RANK, dtproj_b + (size_t)i * D_INNER,
        A_log + (size_t)i * D_INNER * D_STATE, Dskip + (size_t)i * D_INNER, buf_yb);

    // out_proj (bf16 MFMA, fp32 out): h = y @ out_W^T   (M, 512)
    k_gemm_mfma<0><<<dim3(512 / 128, M_PAD / 128), blk, 0, stream>>>(
        buf_yb, buf_wob, buf_h, 512, M_ROWS, 512, 1024);
  }

  // final residual + rmsnorm -> xf (bf16, over hnb region; y dead)
  k_resid_norm<<<(M_ROWS + 3) / 4, blk, 0, stream>>>(
      buf_h, buf_res, nullptr, buf_hnb, normf_w, normf_b, 1, 1);

  // head_W -> bf16 padded to 256 rows (reuse in_W bf16 buffer — dead after last in_proj)
  k_f2b<<<(256 * 512 + 255) / 256, blk, 0, stream>>>(head_W, buf_wib, CITY * 512, 256 * 512);

  // head (bf16 MFMA, fp32 out): logits = xf @ head_W^T   (M, 200), N padded to 256
  k_gemm_mfma<0><<<dim3(256 / 128, M_PAD / 128), blk, 0, stream>>>(
      buf_hnb, buf_wib, out, CITY, M_ROWS, CITY, 512);
}

// Round 9
// 1045.174 us; speedup vs baseline: 1.1340x; 1.1340x over previous
//
#include <hip/hip_runtime.h>
#include <math.h>

#define D_MODEL 512
#define D_INNER 1024
#define DT_RANK 32
#define D_STATE 16
#define D_CONV 4
#define NB_LAYERS 3
#define BATCH 64
#define SEQ 201
#define CITY 200
#define M_ROWS (BATCH * SEQ)   // 12864 = 64*201
#define M_PAD 12928            // 128*101, for 128-row MFMA tiles
#define EPS 1e-5f
#define ST 16                  // scan timestep tile

typedef __attribute__((ext_vector_type(8))) short short8;
typedef __attribute__((ext_vector_type(4))) float f32x4;

__device__ __forceinline__ float sigmoidf_(float x) { return 1.f / (1.f + __expf(-x)); }

__device__ __forceinline__ unsigned short f2b(float f) {  // RNE fp32->bf16
  union { float f; unsigned int u; } v; v.f = f;
  unsigned int r = (v.u + 0x7fff + ((v.u >> 16) & 1)) >> 16;
  return (unsigned short)r;
}
__device__ __forceinline__ float b2f(unsigned short h) {
  union { unsigned int u; float f; } v; v.u = ((unsigned int)h) << 16; return v.f;
}

__device__ __forceinline__ void gload_lds16(const void* g, void* l) {
  __builtin_amdgcn_global_load_lds(
      (const __attribute__((address_space(1))) void*)g,
      (__attribute__((address_space(3))) void*)l, 16, 0, 0);
}

// ---------------- fp32 -> bf16 bulk convert (zero-pad tail to n_total) ----------------
__global__ __launch_bounds__(256) void k_f2b(const float* __restrict__ in,
                                             unsigned short* __restrict__ out,
                                             int n, int n_total) {
  int i = blockIdx.x * 256 + threadIdx.x;
  if (i < n) out[i] = f2b(in[i]);
  else if (i < n_total) out[i] = 0;
}

// ---------------- embed ----------------
__global__ __launch_bounds__(256) void k_embed(const float* __restrict__ x,
                                               const float* __restrict__ W,
                                               const float* __restrict__ b,
                                               float* __restrict__ h) {
  int idx = blockIdx.x * 256 + threadIdx.x;
  if (idx >= M_ROWS * D_MODEL) return;
  int d = idx & (D_MODEL - 1);
  int m = idx >> 9;
  float x0 = x[m * 2 + 0], x1 = x[m * 2 + 1];
  h[idx] = fmaf(x0, W[d * 2 + 0], fmaf(x1, W[d * 2 + 1], b[d]));
}

// ---------------- fused residual add + LayerNorm / RMSNorm ----------------
__global__ __launch_bounds__(256) void k_resid_norm(const float* __restrict__ h,
                                                    float* __restrict__ resid,
                                                    float* __restrict__ out,
                                                    unsigned short* __restrict__ out_b,
                                                    const float* __restrict__ w,
                                                    const float* __restrict__ b,
                                                    int addRes, int mode) {
  int row = blockIdx.x * 4 + (threadIdx.x >> 6);
  int lane = threadIdx.x & 63;
  if (row >= M_ROWS) return;
  const float* hp = h + (size_t)row * D_MODEL;
  float* rp = resid + (size_t)row * D_MODEL;
  float v[8];
#pragma unroll
  for (int j = 0; j < 8; ++j) {
    float t = hp[j * 64 + lane];
    if (addRes) t += rp[j * 64 + lane];
    v[j] = t;
    rp[j * 64 + lane] = t;
  }
  float mu = 0.f, rstd;
  if (mode == 0) {
    float s = 0.f;
#pragma unroll
    for (int j = 0; j < 8; ++j) s += v[j];
#pragma unroll
    for (int o = 1; o < 64; o <<= 1) s += __shfl_xor(s, o);
    mu = s * (1.f / D_MODEL);
    float vs = 0.f;
#pragma unroll
    for (int j = 0; j < 8; ++j) { float d0 = v[j] - mu; vs += d0 * d0; }
#pragma unroll
    for (int o = 1; o < 64; o <<= 1) vs += __shfl_xor(vs, o);
    rstd = rsqrtf(vs * (1.f / D_MODEL) + EPS);
  } else {
    float s = 0.f;
#pragma unroll
    for (int j = 0; j < 8; ++j) s += v[j] * v[j];
#pragma unroll
    for (int o = 1; o < 64; o <<= 1) s += __shfl_xor(s, o);
    rstd = rsqrtf(s * (1.f / D_MODEL) + EPS);
  }
#pragma unroll
  for (int j = 0; j < 8; ++j) {
    int c = j * 64 + lane;
    float o = (v[j] - mu) * rstd * w[c] + b[c];
    if (out) out[(size_t)row * D_MODEL + c] = o;
    if (out_b) out_b[(size_t)row * D_MODEL + c] = f2b(o);
  }
}

// ---------------- bf16 MFMA GEMM: C[M,Nout] = A[M,K]bf16 @ B[N,K]bf16^T ----------
// BM=BN=128, BK=64, 256 threads (4 waves, 2x2 of 64x64). Ngrid%128==0, K%64==0.
// BOUT=1 -> bf16 output, else fp32. Store guarded by m<M && col<Nout.
template <int BOUT>
__global__ __launch_bounds__(256) void k_gemm_mfma(const unsigned short* __restrict__ A,
                                                   const unsigned short* __restrict__ B,
                                                   void* __restrict__ Cv, int ldc,
                                                   int M, int Nout, int K) {
  __shared__ unsigned short lA[128 * 64];
  __shared__ unsigned short lB[128 * 64];
  int tid = threadIdx.x;
  int wave = tid >> 6, lane = tid & 63;
  int bm = blockIdx.y * 128, bn = blockIdx.x * 128;
  int wm = (wave >> 1) * 64, wn = (wave & 1) * 64;
  f32x4 acc[4][4] = {};

  for (int k0 = 0; k0 < K; k0 += 64) {
#pragma unroll
    for (int i = 0; i < 4; ++i) {
      int e = (i * 256 + tid) * 8;   // flat bf16 element in [128][64] tile
      int r = e >> 6, c = e & 63;
      gload_lds16(A + (size_t)(bm + r) * K + k0 + c, &lA[e]);
      gload_lds16(B + (size_t)(bn + r) * K + k0 + c, &lB[e]);
    }
    __syncthreads();
#pragma unroll
    for (int ks = 0; ks < 2; ++ks) {
      int koff = ks * 32 + (lane >> 4) * 8;
      short8 a[4], b[4];
#pragma unroll
      for (int i = 0; i < 4; ++i)
        a[i] = *(const short8*)&lA[(wm + i * 16 + (lane & 15)) * 64 + koff];
#pragma unroll
      for (int j = 0; j < 4; ++j)
        b[j] = *(const short8*)&lB[(wn + j * 16 + (lane & 15)) * 64 + koff];
#pragma unroll
      for (int i = 0; i < 4; ++i)
#pragma unroll
        for (int j = 0; j < 4; ++j)
          acc[i][j] = __builtin_amdgcn_mfma_f32_16x16x32_bf16(a[i], b[j], acc[i][j], 0, 0, 0);
    }
    __syncthreads();
  }
  // C/D layout: col = lane&15, row = (lane>>4)*4 + reg   [m89-verified]
#pragma unroll
  for (int i = 0; i < 4; ++i) {
    int row0 = bm + wm + i * 16 + (lane >> 4) * 4;
#pragma unroll
    for (int j = 0; j < 4; ++j) {
      int col = bn + wn + j * 16 + (lane & 15);
#pragma unroll
      for (int r = 0; r < 4; ++r) {
        int m = row0 + r;
        if (m < M && col < Nout) {
          if (BOUT) ((unsigned short*)Cv)[(size_t)m * ldc + col] = f2b(acc[i][j][r]);
          else ((float*)Cv)[(size_t)m * ldc + col] = acc[i][j][r];
        }
      }
    }
  }
}

// ---------------- depthwise causal conv (width 4) + bias + SiLU; bf16 in/out --------------
__global__ __launch_bounds__(256) void k_conv_silu(const unsigned short* __restrict__ xz,
                                                   const float* __restrict__ cw,
                                                   const float* __restrict__ cb,
                                                   unsigned short* __restrict__ ub) {
  int idx = blockIdx.x * 256 + threadIdx.x;
  if (idx >= M_ROWS * D_INNER) return;
  int d = idx & (D_INNER - 1);
  int m = idx >> 10;
  int l = m % SEQ;
  float acc = cb[d];
#pragma unroll
  for (int k = 0; k < D_CONV; ++k) {
    int ls = l - (D_CONV - 1) + k;
    if (ls >= 0)
      acc = fmaf(cw[d * D_CONV + k], b2f(xz[(size_t)(m - (D_CONV - 1) + k) * 2048 + d]), acc);
  }
  ub[idx] = f2b(acc * sigmoidf_(acc));
}

// ---------------- selective scan + fused dt_proj + D-skip + z-gate (phase-split) ----------
// 1 thread/channel. Per 16-step tile:
//   A) batch-issue u/z loads (one vmcnt drain/tile) + stage xdbl rows to LDS
//   B) 16 INDEPENDENT dt dots (4-acc trees) + fast softplus  -> dtv[16]
//   C) 16 sequential steps; only hst[n] chains are serial; exps/LDS reads pipeline.
// Loads/compute unconditional (tail reads stay inside d_ws; hst garbage only after last use);
// only the y-store is guarded (would overwrite next batch's rows).
__global__ __launch_bounds__(256) void k_scan(const unsigned short* __restrict__ xz,
                                              const unsigned short* __restrict__ ub,
                                              const float* __restrict__ xdbl,
                                              const float* __restrict__ dtW,
                                              const float* __restrict__ dtb,
                                              const float* __restrict__ A_log,
                                              const float* __restrict__ Dv,
                                              unsigned short* __restrict__ yb) {
  __shared__ float lxd[ST][64];
  int tid = threadIdx.x;
  int d = blockIdx.y * 256 + tid;
  int b = blockIdx.x;

  float Wd[DT_RANK];
#pragma unroll
  for (int r = 0; r < DT_RANK; r += 4) {
    float4 w4 = *(const float4*)&dtW[(size_t)d * DT_RANK + r];
    Wd[r] = w4.x; Wd[r + 1] = w4.y; Wd[r + 2] = w4.z; Wd[r + 3] = w4.w;
  }
  float bias = dtb[d];
  float Areg[D_STATE], hst[D_STATE];
#pragma unroll
  for (int n = 0; n < D_STATE; ++n) {
    Areg[n] = -__expf(A_log[d * D_STATE + n]);
    hst[n] = 0.f;
  }
  float Dd = Dv[d];
  size_t row0 = (size_t)b * SEQ;

  for (int t0 = 0; t0 < SEQ; t0 += ST) {
    int nt = SEQ - t0 < ST ? SEQ - t0 : ST;  // wave-uniform
    // ---- phase A: batch-issue u/z loads (unconditional, stay within d_ws) ----
    float uv[ST], zv[ST];
#pragma unroll
    for (int tt = 0; tt < ST; ++tt) {
      size_t m = row0 + t0 + tt;
      uv[tt] = b2f(ub[m * D_INNER + d]);
      zv[tt] = b2f(xz[m * 2048 + 1024 + d]);
    }
#pragma unroll
    for (int tt = 0; tt < ST; ++tt)
      asm volatile("" :: "v"(uv[tt]), "v"(zv[tt]));
    __syncthreads();  // previous tile's LDS consumers done
    {
      float4 v = *(const float4*)&xdbl[(row0 + t0 + (tid >> 4)) * 64 + (tid & 15) * 4];
      *(float4*)&lxd[tid >> 4][(tid & 15) * 4] = v;
    }
    __syncthreads();
    // ---- phase B: 16 independent dt dots, 4 accumulators each ----
    float dtv[ST];
#pragma unroll
    for (int tt = 0; tt < ST; ++tt) {
      float a0 = bias, a1 = 0.f, a2 = 0.f, a3 = 0.f;
#pragma unroll
      for (int r = 0; r < 8; r += 4) {
        float4 q0 = *(const float4*)&lxd[tt][(r + 0) * 4];
        float4 q1 = *(const float4*)&lxd[tt][(r + 1) * 4];
        float4 q2 = *(const float4*)&lxd[tt][(r + 2) * 4];
        float4 q3 = *(const float4*)&lxd[tt][(r + 3) * 4];
        a0 = fmaf(q0.x, Wd[4 * r + 0], a0); a0 = fmaf(q0.y, Wd[4 * r + 1], a0);
        a0 = fmaf(q0.z, Wd[4 * r + 2], a0); a0 = fmaf(q0.w, Wd[4 * r + 3], a0);
        a1 = fmaf(q1.x, Wd[4 * r + 4], a1); a1 = fmaf(q1.y, Wd[4 * r + 5], a1);
        a1 = fmaf(q1.z, Wd[4 * r + 6], a1); a1 = fmaf(q1.w, Wd[4 * r + 7], a1);
        a2 = fmaf(q2.x, Wd[4 * r + 8], a2); a2 = fmaf(q2.y, Wd[4 * r + 9], a2);
        a2 = fmaf(q2.z, Wd[4 * r + 10], a2); a2 = fmaf(q2.w, Wd[4 * r + 11], a2);
        a3 = fmaf(q3.x, Wd[4 * r + 12], a3); a3 = fmaf(q3.y, Wd[4 * r + 13], a3);
        a3 = fmaf(q3.z, Wd[4 * r + 14], a3); a3 = fmaf(q3.w, Wd[4 * r + 15], a3);
      }
      float dot = (a0 + a1) + (a2 + a3);
      dtv[tt] = (dot > 20.f) ? dot : __logf(1.f + __expf(dot));
    }
    // ---- phase C: sequential recurrence ----
#pragma unroll
    for (int tt = 0; tt < ST; ++tt) {
      float du = dtv[tt] * uv[tt];
      float y0 = 0.f, y1 = 0.f, y2 = 0.f, y3 = 0.f;
#pragma unroll
      for (int q = 0; q < 4; ++q) {
        float4 vb = *(const float4*)&lxd[tt][32 + q * 4];
        float4 vc = *(const float4*)&lxd[tt][48 + q * 4];
        float& yq = (q == 0) ? y0 : (q == 1) ? y1 : (q == 2) ? y2 : y3;
        hst[4 * q + 0] = fmaf(__expf(dtv[tt] * Areg[4 * q + 0]), hst[4 * q + 0], du * vb.x);
        yq = fmaf(hst[4 * q + 0], vc.x, yq);
        hst[4 * q + 1] = fmaf(__expf(dtv[tt] * Areg[4 * q + 1]), hst[4 * q + 1], du * vb.y);
        yq = fmaf(hst[4 * q + 1], vc.y, yq);
        hst[4 * q + 2] = fmaf(__expf(dtv[tt] * Areg[4 * q + 2]), hst[4 * q + 2], du * vb.z);
        yq = fmaf(hst[4 * q + 2], vc.z, yq);
        hst[4 * q + 3] = fmaf(__expf(dtv[tt] * Areg[4 * q + 3]), hst[4 * q + 3], du * vb.w);
        yq = fmaf(hst[4 * q + 3], vc.w, yq);
      }
      float y = (y0 + y1) + (y2 + y3);
      y = fmaf(Dd, uv[tt], y);
      y = y * (zv[tt] * sigmoidf_(zv[tt]));
      if (tt < nt) yb[(row0 + t0 + tt) * D_INNER + d] = f2b(y);
    }
  }
}

extern "C" void kernel_launch(void* const* d_in, const int* in_sizes, int n_in,
                              void* d_out, int out_size, void* d_ws, size_t ws_size,
                              hipStream_t stream) {
  const float* x        = (const float*)d_in[0];
  const float* embed_W  = (const float*)d_in[2];
  const float* embed_b  = (const float*)d_in[3];
  const float* norm_w   = (const float*)d_in[4];
  const float* norm_b   = (const float*)d_in[5];
  const float* in_W     = (const float*)d_in[6];
  const float* conv_w   = (const float*)d_in[7];
  const float* conv_b   = (const float*)d_in[8];
  const float* xproj_W  = (const float*)d_in[9];
  const float* dtproj_W = (const float*)d_in[10];
  const float* dtproj_b = (const float*)d_in[11];
  const float* A_log    = (const float*)d_in[12];
  const float* Dskip    = (const float*)d_in[13];
  const float* out_W    = (const float*)d_in[14];
  const float* normf_w  = (const float*)d_in[15];
  const float* normf_b  = (const float*)d_in[16];
  const float* head_W   = (const float*)d_in[17];
  float* out = (float*)d_out;

  // fp32: res 512 + h 512 + xdbl 64 = M*1088 (56 MiB)
  // bf16: xz M*2048 + ub/yb M_PAD*2048 + weights (~1.7M elems)  (~109 MiB)
  size_t f32_elems = (size_t)M_ROWS * 1088;
  size_t bf16_elems = (size_t)M_ROWS * 2048 + (size_t)M_PAD * 2048 +
                      2048 * 512 + 512 * 1024 + 128 * 1024;
  size_t need = f32_elems * 4 + bf16_elems * 2;
  if (ws_size < need) return;

  float* ws = (float*)d_ws;
  float* buf_res  = ws;                                   // M*512
  float* buf_h    = buf_res  + (size_t)M_ROWS * 512;      // M*512
  float* buf_xdbl = buf_h    + (size_t)M_ROWS * 512;      // M*64
  unsigned short* buf_xz  = (unsigned short*)(buf_xdbl + (size_t)M_ROWS * 64); // M*2048 (xc|z)
  unsigned short* buf_ub  = buf_xz + (size_t)M_ROWS * 2048;  // M_PAD*1024
  unsigned short* buf_yb  = buf_ub + (size_t)M_PAD * 1024;   // M_PAD*1024 (alias hnb)
  unsigned short* buf_hnb = buf_yb;                          // M_PAD*512 (hn dead before scan)
  unsigned short* buf_wib = buf_yb + (size_t)M_PAD * 1024;   // 2048*512 (in_W; head_W after loop)
  unsigned short* buf_wob = buf_wib + (size_t)2048 * 512;    // 512*1024 (out_W)
  unsigned short* buf_wxb = buf_wob + (size_t)512 * 1024;    // 128*1024 (xproj_W padded)

  dim3 blk(256);

  k_embed<<<(M_ROWS * D_MODEL + 255) / 256, blk, 0, stream>>>(x, embed_W, embed_b, buf_h);

  for (int i = 0; i < NB_LAYERS; ++i) {
    // weights -> bf16 (per layer); xproj_W zero-padded 64->128 rows
    k_f2b<<<(2048 * 512 + 255) / 256, blk, 0, stream>>>(
        in_W + (size_t)i * 2048 * D_MODEL, buf_wib, 2048 * 512, 2048 * 512);
    k_f2b<<<(512 * 1024 + 255) / 256, blk, 0, stream>>>(
        out_W + (size_t)i * D_MODEL * D_INNER, buf_wob, 512 * 1024, 512 * 1024);
    k_f2b<<<(128 * 1024 + 255) / 256, blk, 0, stream>>>(
        xproj_W + (size_t)i * 64 * D_INNER, buf_wxb, 64 * 1024, 128 * 1024);

    // residual update + layernorm -> hn (bf16)
    k_resid_norm<<<(M_ROWS + 3) / 4, blk, 0, stream>>>(
        buf_h, buf_res, nullptr, buf_hnb, norm_w + i * D_MODEL, norm_b + i * D_MODEL,
        i > 0 ? 1 : 0, 0);

    // in_proj (bf16 MFMA, bf16 out): xz = hn @ in_W^T   (M, 2048)
    k_gemm_mfma<1><<<dim3(2048 / 128, M_PAD / 128), blk, 0, stream>>>(
        buf_hnb, buf_wib, buf_xz, 2048, M_ROWS, 2048, 512);

    // conv + silu -> u (bf16 in/out)
    k_conv_silu<<<(M_ROWS * D_INNER + 255) / 256, blk, 0, stream>>>(
        buf_xz, conv_w + (size_t)i * D_INNER * D_CONV, conv_b + (size_t)i * D_INNER, buf_ub);

    // x_proj (bf16 MFMA, fp32 out): xdbl = u @ xproj_W^T   (M, 64), N padded to 128
    k_gemm_mfma<0><<<dim3(1, M_PAD / 128), blk, 0, stream>>>(
        buf_ub, buf_wxb, buf_xdbl, 64, M_ROWS, 64, 1024);

    // selective scan (fused dt_proj, phase-split) -> y (bf16)
    k_scan<<<dim3(BATCH, D_INNER / 256), blk, 0, stream>>>(
        buf_xz, buf_ub, buf_xdbl,
        dtproj_W + (size_t)i * D_INNER * DT_RANK, dtproj_b + (size_t)i * D_INNER,
        A_log + (size_t)i * D_INNER * D_STATE, Dskip + (size_t)i * D_INNER, buf_yb);

    // out_proj (bf16 MFMA, fp32 out): h = y @ out_W^T   (M, 512)
    k_gemm_mfma<0><<<dim3(512 / 128, M_PAD / 128), blk, 0, stream>>>(
        buf_yb, buf_wob, buf_h, 512, M_ROWS, 512, 1024);
  }

  // final residual + rmsnorm -> xf (bf16, over hnb region; y dead)
  k_resid_norm<<<(M_ROWS + 3) / 4, blk, 0, stream>>>(
      buf_h, buf_res, nullptr, buf_hnb, normf_w, normf_b, 1, 1);

  // head_W -> bf16 padded to 256 rows (reuse in_W bf16 buffer — dead after last in_proj)
  k_f2b<<<(256 * 512 + 255) / 256, blk, 0, stream>>>(head_W, buf_wib, CITY * 512, 256 * 512);

  // head (bf16 MFMA, fp32 out): logits = xf @ head_W^T   (M, 200), N padded to 256
  k_gemm_mfma<0><<<dim3(256 / 128, M_PAD / 128), blk, 0, stream>>>(
      buf_hnb, buf_wib, out, CITY, M_ROWS, CITY, 512);
}